// Round 1
// baseline (236.960 us; speedup 1.0000x reference)
//
#include <hip/hip_runtime.h>
#include <hip/hip_bf16.h>
#include <math.h>

// Problem constants (B=8, T=1024, EMB=768, H=12, D=64)
#define BATCH 8
#define SEQ   1024
#define EMB   768
#define NH    12
#define HD    64
#define QKVW  (3 * EMB)   // 2304
#define VOFF  (2 * EMB)   // 1536 — start of V columns in qkv

typedef short short8   __attribute__((ext_vector_type(8)));
typedef float floatx4  __attribute__((ext_vector_type(4)));

// fp32 -> bf16 (RNE) as raw short
__device__ __forceinline__ short f2bf(float f) {
    union { float f; unsigned u; } v; v.f = f;
    unsigned r = (v.u + 0x7fffu + ((v.u >> 16) & 1u)) >> 16;
    return (short)r;
}

// async 16B global -> LDS (wave-uniform base + lane*16 on the LDS side)
__device__ __forceinline__ void async_load16(const void* g, void* l) {
    __builtin_amdgcn_global_load_lds(
        (const __attribute__((address_space(1))) unsigned int*)g,
        (__attribute__((address_space(3))) unsigned int*)l, 16, 0, 0);
}

// ---------------------------------------------------------------------------
// fp32 -> bf16 elementwise (8 elems/thread)
// ---------------------------------------------------------------------------
__global__ __launch_bounds__(256) void cvt_bf16(
    const float* __restrict__ in, short* __restrict__ out, int n8)
{
    const int i = blockIdx.x * 256 + threadIdx.x;
    if (i >= n8) return;
    const float4 a = ((const float4*)in)[2 * i];
    const float4 b = ((const float4*)in)[2 * i + 1];
    short8 s;
    s[0] = f2bf(a.x); s[1] = f2bf(a.y); s[2] = f2bf(a.z); s[3] = f2bf(a.w);
    s[4] = f2bf(b.x); s[5] = f2bf(b.y); s[6] = f2bf(b.z); s[7] = f2bf(b.w);
    ((short8*)out)[i] = s;
}

// ---------------------------------------------------------------------------
// fp32 [R,C] -> bf16 [C,R] (transpose). R,C multiples of 32. Block 256 = 32x8.
// ---------------------------------------------------------------------------
__global__ __launch_bounds__(256) void transpose_to_bf16(
    const float* __restrict__ in, short* __restrict__ outT, int R, int C)
{
    __shared__ float t[32][33];
    const int c0 = blockIdx.x * 32, r0 = blockIdx.y * 32;
    const int lx = threadIdx.x & 31, ly = threadIdx.x >> 5;
    #pragma unroll
    for (int i = 0; i < 32; i += 8)
        t[ly + i][lx] = in[(size_t)(r0 + ly + i) * C + c0 + lx];
    __syncthreads();
    #pragma unroll
    for (int i = 0; i < 32; i += 8)
        outT[(size_t)(c0 + ly + i) * R + r0 + lx] = f2bf(t[lx][ly + i]);
}

// ---------------------------------------------------------------------------
// Legacy 128x128 bf16 MFMA GEMM (kept for the proj GEMM, MODE 0 only).
// ---------------------------------------------------------------------------
#define GBK 64

template <int MODE>
__global__ __launch_bounds__(256) void gemm_bf16(
    const short* __restrict__ A, const short* __restrict__ Bt,
    const float* __restrict__ bias, void* __restrict__ Cout,
    short* __restrict__ vt, int M, int N, int K)
{
    __shared__ __align__(16) short As[128 * GBK];   // 16 KB
    __shared__ __align__(16) short Bs[128 * GBK];   // 16 KB

    const int tid  = threadIdx.x;
    const int wave = tid >> 6;
    const int lane = tid & 63;
    const int ln15 = lane & 15;
    const int quad = lane >> 4;
    const int wr   = (wave >> 1) * 64;
    const int wc   = (wave & 1) * 64;
    const int row0 = blockIdx.y * 128;
    const int col0 = blockIdx.x * 128;

    const bool trans = (MODE == 0) || (col0 < VOFF);

    floatx4 acc[4][4];
    #pragma unroll
    for (int i = 0; i < 4; ++i)
        #pragma unroll
        for (int j = 0; j < 4; ++j) acc[i][j] = (floatx4){0.f, 0.f, 0.f, 0.f};

    for (int k0 = 0; k0 < K; k0 += GBK) {
        __syncthreads();
        #pragma unroll
        for (int p = 0; p < 4; ++p) {
            const int id  = p * 256 + tid;
            const int row = id >> 3;
            const int c   = (id & 7) ^ (row & 7);
            async_load16(A  + (size_t)(row0 + row) * K + k0 + c * 8, &As[id * 8]);
            async_load16(Bt + (size_t)(col0 + row) * K + k0 + c * 8, &Bs[id * 8]);
        }
        __syncthreads();

        #pragma unroll
        for (int half = 0; half < 2; ++half) {
            short8 af[4], bf[4];
            #pragma unroll
            for (int t = 0; t < 4; ++t) {
                const int ch = ((quad + half * 4) ^ (ln15 & 7)) * 8;
                af[t] = *(const short8*)&As[(wr + t * 16 + ln15) * GBK + ch];
                bf[t] = *(const short8*)&Bs[(wc + t * 16 + ln15) * GBK + ch];
            }
            if (trans) {
                #pragma unroll
                for (int i = 0; i < 4; ++i)
                    #pragma unroll
                    for (int j = 0; j < 4; ++j)
                        acc[i][j] = __builtin_amdgcn_mfma_f32_16x16x32_bf16(bf[j], af[i], acc[i][j], 0, 0, 0);
            } else {
                #pragma unroll
                for (int i = 0; i < 4; ++i)
                    #pragma unroll
                    for (int j = 0; j < 4; ++j)
                        acc[i][j] = __builtin_amdgcn_mfma_f32_16x16x32_bf16(af[i], bf[j], acc[i][j], 0, 0, 0);
            }
        }
    }

    if (MODE == 1 && !trans) {
        #pragma unroll
        for (int j = 0; j < 4; ++j) {
            const int c  = col0 + wc + j * 16 + ln15;
            const float bv = bias[c];
            const int c2 = c - VOFF;
            #pragma unroll
            for (int i = 0; i < 4; ++i) {
                const int r = row0 + wr + i * 16 + quad * 4;
                union { short s[4]; unsigned long long u; } pk;
                #pragma unroll
                for (int reg = 0; reg < 4; ++reg)
                    pk.s[reg] = f2bf(acc[i][j][reg] + bv);
                *(unsigned long long*)&vt[(size_t)(r >> 10) * (EMB * SEQ) +
                                          (size_t)c2 * SEQ + (r & 1023)] = pk.u;
            }
        }
    } else {
        float4 b4[4];
        #pragma unroll
        for (int j = 0; j < 4; ++j)
            b4[j] = *(const float4*)&bias[col0 + wc + j * 16 + quad * 4];
        #pragma unroll
        for (int i = 0; i < 4; ++i) {
            const int r = row0 + wr + i * 16 + ln15;
            #pragma unroll
            for (int j = 0; j < 4; ++j) {
                const int c = col0 + wc + j * 16 + quad * 4;
                if (MODE == 1) {
                    union { short s[4]; unsigned long long u; } pk;
                    pk.s[0] = f2bf(acc[i][j][0] + b4[j].x);
                    pk.s[1] = f2bf(acc[i][j][1] + b4[j].y);
                    pk.s[2] = f2bf(acc[i][j][2] + b4[j].z);
                    pk.s[3] = f2bf(acc[i][j][3] + b4[j].w);
                    *(unsigned long long*)&((short*)Cout)[(size_t)r * N + c] = pk.u;
                } else {
                    float4 v;
                    v.x = acc[i][j][0] + b4[j].x;
                    v.y = acc[i][j][1] + b4[j].y;
                    v.z = acc[i][j][2] + b4[j].z;
                    v.w = acc[i][j][3] + b4[j].w;
                    *(float4*)&((float*)Cout)[(size_t)r * N + c] = v;
                }
            }
        }
    }
}

// ---------------------------------------------------------------------------
// QKV GEMM, 256x256 tile / BK=64 / 8 waves (2Mx4N), 8-phase schedule with
// counted vmcnt (T3+T4), setprio around MFMA clusters (T5), XOR-swizzled
// staging via pre-swizzled global source + swizzled ds_read (T2, rule 21),
// XCD-bijective block swizzle (T1; grid 288 % 8 == 0).
//
// Per K-tile (4 phases): P1 (m0-3 x n0-1, 12 ds_reads), P2 (m0-3 x n2-3, 4),
// P3 (m4-7 x n2-3, 8), P4 (m4-7 x n0-1, 0).  Staging: tile T's half0 issued
// at P4 of tile T-2, halves 1-3 at P1-3 of tile T-1; vmcnt(2) once per K-tile
// at P4 guarantees tile T complete before its P1 reads — loads are never
// drained to 0 in steady state.
// ---------------------------------------------------------------------------
#define NT12 (EMB / 64)   // 12 K-tiles

#define BAR()    do { asm volatile("" ::: "memory"); __builtin_amdgcn_s_barrier(); \
                      asm volatile("" ::: "memory"); } while (0)
#define LGKM0()  asm volatile("s_waitcnt lgkmcnt(0)" ::: "memory")
#define VMC0()   asm volatile("s_waitcnt vmcnt(0)" ::: "memory")
#define VMC2()   asm volatile("s_waitcnt vmcnt(2)" ::: "memory")
#define VMC8()   asm volatile("s_waitcnt vmcnt(8)" ::: "memory")
#define SCHED0() __builtin_amdgcn_sched_barrier(0)
#define PRIO1()  __builtin_amdgcn_s_setprio(1)
#define PRIO0()  __builtin_amdgcn_s_setprio(0)

// swizzled fragment read: logical k-chunk q of row r lives at physical chunk q^(r&7)
#define LDA(bf_, r_, q_) (*(const short8*)&As[bf_][(r_) * 64 + ((((q_)) ^ ((r_) & 7)) << 3)])
#define LDB(bf_, r_, q_) (*(const short8*)&Bs[bf_][(r_) * 64 + ((((q_)) ^ ((r_) & 7)) << 3)])

// 16 MFMAs: acc[IB..IB+3][JB..JB+1], both k-halves. Static indices only (rule 20).
#define MMA8(IB, JB)                                                                   \
    _Pragma("unroll")                                                                  \
    for (int mi = 0; mi < 4; ++mi)                                                     \
        _Pragma("unroll")                                                              \
        for (int nj = 0; nj < 2; ++nj)                                                 \
            _Pragma("unroll")                                                          \
            for (int kk = 0; kk < 2; ++kk) {                                           \
                if (vpath)                                                             \
                    acc[(IB) + mi][(JB) + nj] = __builtin_amdgcn_mfma_f32_16x16x32_bf16( \
                        a[mi][kk], b[(JB) + nj][kk], acc[(IB) + mi][(JB) + nj], 0, 0, 0); \
                else                                                                   \
                    acc[(IB) + mi][(JB) + nj] = __builtin_amdgcn_mfma_f32_16x16x32_bf16( \
                        b[(JB) + nj][kk], a[mi][kk], acc[(IB) + mi][(JB) + nj], 0, 0, 0); \
            }

__global__ __launch_bounds__(512, 2) void gemm_qkv_256(
    const short* __restrict__ A, const short* __restrict__ Bt,
    const float* __restrict__ bias, short* __restrict__ qkvb,
    short* __restrict__ vt)
{
    __shared__ __align__(16) short As[2][256 * 64];   // 64 KB (2 K-tile buffers)
    __shared__ __align__(16) short Bs[2][256 * 64];   // 64 KB

    const int tid  = threadIdx.x;
    const int wave = tid >> 6;
    const int lane = tid & 63;
    const int ln15 = lane & 15;
    const int quad = lane >> 4;
    const int wm   = wave >> 2;        // 0..1  (M direction, 128 rows each)
    const int wn   = wave & 3;         // 0..3  (N direction, 64 cols each)

    // XCD-bijective swizzle: 288 blocks, 36 consecutive tiles per XCD
    const int orig = blockIdx.x;
    const int wg   = (orig & 7) * 36 + (orig >> 3);
    const int bx   = wg % (QKVW / 256);   // 0..8
    const int by   = wg / (QKVW / 256);   // 0..31
    const int row0 = by * 256;
    const int col0 = bx * 256;
    const bool vpath = (col0 >= VOFF);    // tiles 6,7,8 are the V columns

    const short* Ag = A  + (size_t)row0 * EMB;
    const short* Bg = Bt + (size_t)col0 * EMB;

    // stage one half-tile of K-tile t: h = 0 (A rows 0-127), 1 (A 128-255),
    // 2 (B rows 0-127), 3 (B 128-255). 2 global_load_lds per wave per call.
    auto stage_half = [&](int t, int h) {
        if (t >= NT12) return;
        const int buf   = t & 1;
        const int k0    = t * 64;
        const int rbase = (h & 1) * 128;
        short* lb       = (h < 2) ? &As[buf][rbase * 64] : &Bs[buf][rbase * 64];
        const short* gb = (h < 2) ? Ag : Bg;
        #pragma unroll
        for (int p = 0; p < 2; ++p) {
            const int id  = p * 512 + tid;        // 0..1023
            const int row = rbase + (id >> 3);    // 0..255
            const int c   = (id & 7) ^ (row & 7); // pre-swizzled source chunk
            async_load16(gb + (size_t)row * EMB + k0 + c * 8, lb + (size_t)id * 8);
        }
    };

    floatx4 acc[8][4];
    #pragma unroll
    for (int i = 0; i < 8; ++i)
        #pragma unroll
        for (int j = 0; j < 4; ++j) acc[i][j] = (floatx4){0.f, 0.f, 0.f, 0.f};

    short8 a[4][2];   // current M-half A fragments
    short8 b[4][2];   // all four N fragments (live across phases)

    // ---- prologue: fully stage tiles 0 and 1 (8 loads each per wave) ----
    #pragma unroll
    for (int h = 0; h < 4; ++h) stage_half(0, h);
    #pragma unroll
    for (int h = 0; h < 4; ++h) stage_half(1, h);
    VMC8();           // tile 0 complete; tile 1's 8 loads stay in flight
    BAR();

    const int ar0 = wm * 128 + ln15;
    const int br0 = wn * 64 + ln15;

    for (int kt = 0; kt < NT12; ++kt) {
        const int buf = kt & 1;

        // ---------- phase 1: (m0-3, n0-1) — 12 ds_reads ----------
        #pragma unroll
        for (int mi = 0; mi < 4; ++mi)
            #pragma unroll
            for (int kk = 0; kk < 2; ++kk)
                a[mi][kk] = LDA(buf, ar0 + mi * 16, quad + kk * 4);
        #pragma unroll
        for (int nj = 0; nj < 2; ++nj)
            #pragma unroll
            for (int kk = 0; kk < 2; ++kk)
                b[nj][kk] = LDB(buf, br0 + nj * 16, quad + kk * 4);
        if (kt > 0) stage_half(kt + 1, 1);
        BAR(); LGKM0(); SCHED0();
        PRIO1(); MMA8(0, 0); PRIO0();
        BAR();

        // ---------- phase 2: (m0-3, n2-3) — 4 ds_reads ----------
        #pragma unroll
        for (int nj = 2; nj < 4; ++nj)
            #pragma unroll
            for (int kk = 0; kk < 2; ++kk)
                b[nj][kk] = LDB(buf, br0 + nj * 16, quad + kk * 4);
        if (kt > 0) stage_half(kt + 1, 2);
        BAR(); LGKM0(); SCHED0();
        PRIO1(); MMA8(0, 2); PRIO0();
        BAR();

        // ---------- phase 3: (m4-7, n2-3) — 8 ds_reads ----------
        #pragma unroll
        for (int mi = 0; mi < 4; ++mi)
            #pragma unroll
            for (int kk = 0; kk < 2; ++kk)
                a[mi][kk] = LDA(buf, ar0 + 64 + mi * 16, quad + kk * 4);
        if (kt > 0) stage_half(kt + 1, 3);
        BAR(); LGKM0(); SCHED0();
        PRIO1(); MMA8(4, 2); PRIO0();
        BAR();

        // ---------- phase 4: (m4-7, n0-1) — 0 ds_reads ----------
        // All reads of buffer `buf` completed (phase-3 barrier) -> safe to
        // start overwriting it with tile kt+2.
        stage_half(kt + 2, 0);
        BAR(); SCHED0();
        PRIO1(); MMA8(4, 0); PRIO0();
        if (kt + 2 < NT12) { VMC2(); }   // tile kt+1 complete; kt+2 h0 in flight
        else              { VMC0(); }   // tail: drain everything
        BAR();
    }

    // ---- epilogue (same per-16x16 conventions as the verified 128^2 kernel) ----
    if (!vpath) {
        // trans acc: lane holds row r = ...+ln15, cols c = ...+quad*4+reg
        #pragma unroll
        for (int j = 0; j < 4; ++j) {
            const float4 b4 = *(const float4*)&bias[col0 + wn * 64 + j * 16 + quad * 4];
            #pragma unroll
            for (int i = 0; i < 8; ++i) {
                const int r = row0 + wm * 128 + i * 16 + ln15;
                const int c = col0 + wn * 64 + j * 16 + quad * 4;
                union { short s[4]; unsigned long long u; } pk;
                pk.s[0] = f2bf(acc[i][j][0] + b4.x);
                pk.s[1] = f2bf(acc[i][j][1] + b4.y);
                pk.s[2] = f2bf(acc[i][j][2] + b4.z);
                pk.s[3] = f2bf(acc[i][j][3] + b4.w);
                *(unsigned long long*)&qkvb[(size_t)r * QKVW + c] = pk.u;
            }
        }
    } else {
        // direct acc: lane holds col c = ...+ln15, rows r = ...+quad*4+reg
        #pragma unroll
        for (int j = 0; j < 4; ++j) {
            const int c  = col0 + wn * 64 + j * 16 + ln15;
            const float bv = bias[c];
            const int c2 = c - VOFF;
            #pragma unroll
            for (int i = 0; i < 8; ++i) {
                const int r = row0 + wm * 128 + i * 16 + quad * 4;
                union { short s[4]; unsigned long long u; } pk;
                #pragma unroll
                for (int reg = 0; reg < 4; ++reg)
                    pk.s[reg] = f2bf(acc[i][j][reg] + bv);
                *(unsigned long long*)&vt[(size_t)(r >> 10) * (EMB * SEQ) +
                                          (size_t)c2 * SEQ + (r & 1023)] = pk.u;
            }
        }
    }
}

// ---------------------------------------------------------------------------
// MFMA flash attention — unchanged (passing) version: 64 Q rows/block,
// vt-based V^T staging, no max-tracking, deferred l, swizzled Ps round-trip.
// ---------------------------------------------------------------------------
#define LDK 72  // padded LDS row stride (shorts): 144 B

__global__ __launch_bounds__(256) void attn_mfma(
    const short* __restrict__ qkv, const short* __restrict__ vt,
    short* __restrict__ out)
{
    __shared__ __align__(16) short Ks[64 * LDK];     // K tile [kr][d]
    __shared__ __align__(16) short Vt[64 * LDK];     // V^T tile [d][kr]
    __shared__ __align__(16) short Ps[4 * 16 * LDK]; // per-wave P, swizzled

    const int tid  = threadIdx.x;
    const int wave = tid >> 6;
    const int lane = tid & 63;
    const int ln15 = lane & 15;
    const int quad = lane >> 4;

    const int qc = 15 - (int)(blockIdx.x / (BATCH * NH));   // heavy chunks first
    const int bh = blockIdx.x % (BATCH * NH);
    const int h  = bh % NH;
    const int b  = bh / NH;

    const int q0w = qc * 64 + wave * 16;

    const short* qkv_b = qkv + (size_t)b * SEQ * QKVW + h * HD;
    const short* Kg  = qkv_b + EMB;
    const short* Vtg = vt + ((size_t)b * EMB + h * HD) * SEQ;

    short8 qf[2];
    {
        const short* qrow = qkv_b + (size_t)(q0w + ln15) * QKVW;
        qf[0] = *(const short8*)(qrow + quad * 8);
        qf[1] = *(const short8*)(qrow + quad * 8 + 32);
    }

    floatx4 o[4];
    #pragma unroll
    for (int i = 0; i < 4; ++i) o[i] = (floatx4){0.f, 0.f, 0.f, 0.f};
    float lp[4] = {0.f, 0.f, 0.f, 0.f};   // per-lane l partials

    const int rr = tid >> 3;          // 0..31
    const int c8 = (tid & 7) * 8;     // 0..56

    for (int kt = 0; kt <= qc; ++kt) {
        // ---- stage K rows and V^T rows, b128 writes (conflict-free) ----
        #pragma unroll
        for (int p = 0; p < 2; ++p) {
            const int r2 = rr + p * 32;
            *(uint4*)&Ks[r2 * LDK + c8] =
                *(const uint4*)(Kg + (size_t)(kt * 64 + r2) * QKVW + c8);
            *(uint4*)&Vt[r2 * LDK + c8] =
                *(const uint4*)(Vtg + (size_t)r2 * SEQ + kt * 64 + c8);
        }
        __syncthreads();

        // ---- S = Q · K^T ----
        floatx4 s[4];
        #pragma unroll
        for (int i = 0; i < 4; ++i) s[i] = (floatx4){0.f, 0.f, 0.f, 0.f};
        #pragma unroll
        for (int st = 0; st < 2; ++st)
            #pragma unroll
            for (int sub = 0; sub < 4; ++sub) {
                const short8 kf = *(const short8*)&Ks[(ln15 + sub * 16) * LDK + quad * 8 + st * 32];
                s[sub] = __builtin_amdgcn_mfma_f32_16x16x32_bf16(qf[st], kf, s[sub], 0, 0, 0);
            }

        // ---- P = exp(S/8), causal mask on diagonal tile, accumulate l ----
        const bool diag = (kt == qc);
        #pragma unroll
        for (int sub = 0; sub < 4; ++sub)
            #pragma unroll
            for (int reg = 0; reg < 4; ++reg) {
                float pv = __expf(s[sub][reg] * 0.125f);
                if (diag && (ln15 + sub * 16 > wave * 16 + quad * 4 + reg)) pv = 0.f;
                s[sub][reg] = pv;
            }
        #pragma unroll
        for (int reg = 0; reg < 4; ++reg)
            lp[reg] += (s[0][reg] + s[1][reg]) + (s[2][reg] + s[3][reg]);

        // ---- P (C-layout) -> swizzled LDS -> A-layout fragments ----
        short* Pw = &Ps[wave * 16 * LDK];
        #pragma unroll
        for (int sub = 0; sub < 4; ++sub)
            #pragma unroll
            for (int reg = 0; reg < 4; ++reg) {
                const int qr   = quad * 4 + reg;
                const int kr8  = sub * 2 + (ln15 >> 3);
                const int slot = (kr8 + 5 * quad + reg) & 7;
                Pw[qr * LDK + slot * 8 + (ln15 & 7)] = f2bf(s[sub][reg]);
            }

        short8 pf[2];
        #pragma unroll
        for (int st = 0; st < 2; ++st) {
            const int slot = ((quad + 4 * st) + 5 * (ln15 >> 2) + (ln15 & 3)) & 7;
            pf[st] = *(const short8*)&Pw[ln15 * LDK + slot * 8];
        }

        // ---- O += P · V ----
        #pragma unroll
        for (int st = 0; st < 2; ++st)
            #pragma unroll
            for (int sub = 0; sub < 4; ++sub) {
                const short8 vf = *(const short8*)&Vt[(ln15 + sub * 16) * LDK + quad * 8 + st * 32];
                o[sub] = __builtin_amdgcn_mfma_f32_16x16x32_bf16(pf[st], vf, o[sub], 0, 0, 0);
            }

        __syncthreads();
    }

    // ---- epilogue: reduce l across the 16 lanes of each row, write O/l ----
    #pragma unroll
    for (int reg = 0; reg < 4; ++reg) {
        float t = lp[reg];
        #pragma unroll
        for (int off = 1; off <= 8; off <<= 1)
            t += __shfl_xor(t, off, 64);
        const float inv = 1.0f / t;
        const size_t row = (size_t)(b * SEQ + q0w + quad * 4 + reg) * EMB + h * HD;
        #pragma unroll
        for (int sub = 0; sub < 4; ++sub)
            out[row + ln15 + sub * 16] = f2bf(o[sub][reg] * inv);
    }
}

// ---------------------------------------------------------------------------
extern "C" void kernel_launch(void* const* d_in, const int* in_sizes, int n_in,
                              void* d_out, int out_size, void* d_ws, size_t ws_size,
                              hipStream_t stream)
{
    const float* x      = (const float*)d_in[0];   // [8,1024,768]
    const float* w_attn = (const float*)d_in[1];   // [768, 2304]
    const float* b_attn = (const float*)d_in[2];   // [2304]
    const float* w_proj = (const float*)d_in[3];   // [768, 768]
    const float* b_proj = (const float*)d_in[4];   // [768]
    float* out = (float*)d_out;                    // [8,1024,768] fp32

    const int M = BATCH * SEQ;       // 8192

    short* xb    = (short*)d_ws;                          // [8192, 768]
    short* waT   = xb    + (size_t)M * EMB;               // [2304, 768]
    short* wpT   = waT   + (size_t)QKVW * EMB;            // [768, 768]
    short* qkvb  = wpT   + (size_t)EMB * EMB;             // [8192, 2304] (V third unused)
    short* vtb   = qkvb  + (size_t)M * QKVW;              // [8, 768, 1024] V^T per head
    short* attnb = vtb   + (size_t)BATCH * EMB * SEQ;     // [8192, 768]

    dim3 blk(256);

    // 0) conversions
    cvt_bf16<<<dim3((M * EMB) / 8 / 256), blk, 0, stream>>>(x, xb, (M * EMB) / 8);
    transpose_to_bf16<<<dim3(QKVW / 32, EMB / 32), blk, 0, stream>>>(w_attn, waT, EMB, QKVW);
    transpose_to_bf16<<<dim3(EMB / 32, EMB / 32), blk, 0, stream>>>(w_proj, wpT, EMB, EMB);

    // 1) qkv = x @ w_attn + b_attn  — 256^2 8-phase kernel
    //    (Q/K -> qkvb bf16, V -> vtb transposed). 288 blocks x 512 threads.
    gemm_qkv_256<<<dim3((QKVW / 256) * (M / 256)), dim3(512), 0, stream>>>(
        xb, waT, b_attn, qkvb, vtb);

    // 2) causal MFMA flash attention -> attnb (bf16)
    attn_mfma<<<dim3(16 * BATCH * NH), blk, 0, stream>>>(qkvb, vtb, attnb);

    // 3) out = attn @ w_proj + b_proj  (fp32 out)
    gemm_bf16<0><<<dim3(EMB / 128, M / 128), blk, 0, stream>>>(
        attnb, wpT, b_proj, out, nullptr, M, EMB, EMB);
}

// Round 2
// 216.087 us; speedup vs baseline: 1.0966x; 1.0966x over previous
//
#include <hip/hip_runtime.h>
#include <hip/hip_bf16.h>
#include <math.h>

// Problem constants (B=8, T=1024, EMB=768, H=12, D=64)
#define BATCH 8
#define SEQ   1024
#define EMB   768
#define NH    12
#define HD    64
#define QKVW  (3 * EMB)   // 2304
#define VOFF  (2 * EMB)   // 1536 — start of V columns in qkv

typedef short short8   __attribute__((ext_vector_type(8)));
typedef float floatx4  __attribute__((ext_vector_type(4)));

// fp32 -> bf16 (RNE) as raw short
__device__ __forceinline__ short f2bf(float f) {
    union { float f; unsigned u; } v; v.f = f;
    unsigned r = (v.u + 0x7fffu + ((v.u >> 16) & 1u)) >> 16;
    return (short)r;
}

// async 16B global -> LDS (wave-uniform base + lane*16 on the LDS side)
__device__ __forceinline__ void async_load16(const void* g, void* l) {
    __builtin_amdgcn_global_load_lds(
        (const __attribute__((address_space(1))) unsigned int*)g,
        (__attribute__((address_space(3))) unsigned int*)l, 16, 0, 0);
}

// ---------------------------------------------------------------------------
// fp32 -> bf16 elementwise (8 elems/thread)
// ---------------------------------------------------------------------------
__global__ __launch_bounds__(256) void cvt_bf16(
    const float* __restrict__ in, short* __restrict__ out, int n8)
{
    const int i = blockIdx.x * 256 + threadIdx.x;
    if (i >= n8) return;
    const float4 a = ((const float4*)in)[2 * i];
    const float4 b = ((const float4*)in)[2 * i + 1];
    short8 s;
    s[0] = f2bf(a.x); s[1] = f2bf(a.y); s[2] = f2bf(a.z); s[3] = f2bf(a.w);
    s[4] = f2bf(b.x); s[5] = f2bf(b.y); s[6] = f2bf(b.z); s[7] = f2bf(b.w);
    ((short8*)out)[i] = s;
}

// ---------------------------------------------------------------------------
// fp32 [R,C] -> bf16 [C,R] (transpose). R,C multiples of 32. Block 256 = 32x8.
// ---------------------------------------------------------------------------
__global__ __launch_bounds__(256) void transpose_to_bf16(
    const float* __restrict__ in, short* __restrict__ outT, int R, int C)
{
    __shared__ float t[32][33];
    const int c0 = blockIdx.x * 32, r0 = blockIdx.y * 32;
    const int lx = threadIdx.x & 31, ly = threadIdx.x >> 5;
    #pragma unroll
    for (int i = 0; i < 32; i += 8)
        t[ly + i][lx] = in[(size_t)(r0 + ly + i) * C + c0 + lx];
    __syncthreads();
    #pragma unroll
    for (int i = 0; i < 32; i += 8)
        outT[(size_t)(c0 + ly + i) * R + r0 + lx] = f2bf(t[lx][ly + i]);
}

// ---------------------------------------------------------------------------
// Legacy 128x128 bf16 MFMA GEMM (kept for the proj GEMM, MODE 0 only).
// ---------------------------------------------------------------------------
#define GBK 64

template <int MODE>
__global__ __launch_bounds__(256) void gemm_bf16(
    const short* __restrict__ A, const short* __restrict__ Bt,
    const float* __restrict__ bias, void* __restrict__ Cout,
    short* __restrict__ vt, int M, int N, int K)
{
    __shared__ __align__(16) short As[128 * GBK];   // 16 KB
    __shared__ __align__(16) short Bs[128 * GBK];   // 16 KB

    const int tid  = threadIdx.x;
    const int wave = tid >> 6;
    const int lane = tid & 63;
    const int ln15 = lane & 15;
    const int quad = lane >> 4;
    const int wr   = (wave >> 1) * 64;
    const int wc   = (wave & 1) * 64;
    const int row0 = blockIdx.y * 128;
    const int col0 = blockIdx.x * 128;

    const bool trans = (MODE == 0) || (col0 < VOFF);

    floatx4 acc[4][4];
    #pragma unroll
    for (int i = 0; i < 4; ++i)
        #pragma unroll
        for (int j = 0; j < 4; ++j) acc[i][j] = (floatx4){0.f, 0.f, 0.f, 0.f};

    for (int k0 = 0; k0 < K; k0 += GBK) {
        __syncthreads();
        #pragma unroll
        for (int p = 0; p < 4; ++p) {
            const int id  = p * 256 + tid;
            const int row = id >> 3;
            const int c   = (id & 7) ^ (row & 7);
            async_load16(A  + (size_t)(row0 + row) * K + k0 + c * 8, &As[id * 8]);
            async_load16(Bt + (size_t)(col0 + row) * K + k0 + c * 8, &Bs[id * 8]);
        }
        __syncthreads();

        #pragma unroll
        for (int half = 0; half < 2; ++half) {
            short8 af[4], bf[4];
            #pragma unroll
            for (int t = 0; t < 4; ++t) {
                const int ch = ((quad + half * 4) ^ (ln15 & 7)) * 8;
                af[t] = *(const short8*)&As[(wr + t * 16 + ln15) * GBK + ch];
                bf[t] = *(const short8*)&Bs[(wc + t * 16 + ln15) * GBK + ch];
            }
            if (trans) {
                #pragma unroll
                for (int i = 0; i < 4; ++i)
                    #pragma unroll
                    for (int j = 0; j < 4; ++j)
                        acc[i][j] = __builtin_amdgcn_mfma_f32_16x16x32_bf16(bf[j], af[i], acc[i][j], 0, 0, 0);
            } else {
                #pragma unroll
                for (int i = 0; i < 4; ++i)
                    #pragma unroll
                    for (int j = 0; j < 4; ++j)
                        acc[i][j] = __builtin_amdgcn_mfma_f32_16x16x32_bf16(af[i], bf[j], acc[i][j], 0, 0, 0);
            }
        }
    }

    if (MODE == 1 && !trans) {
        #pragma unroll
        for (int j = 0; j < 4; ++j) {
            const int c  = col0 + wc + j * 16 + ln15;
            const float bv = bias[c];
            const int c2 = c - VOFF;
            #pragma unroll
            for (int i = 0; i < 4; ++i) {
                const int r = row0 + wr + i * 16 + quad * 4;
                union { short s[4]; unsigned long long u; } pk;
                #pragma unroll
                for (int reg = 0; reg < 4; ++reg)
                    pk.s[reg] = f2bf(acc[i][j][reg] + bv);
                *(unsigned long long*)&vt[(size_t)(r >> 10) * (EMB * SEQ) +
                                          (size_t)c2 * SEQ + (r & 1023)] = pk.u;
            }
        }
    } else {
        float4 b4[4];
        #pragma unroll
        for (int j = 0; j < 4; ++j)
            b4[j] = *(const float4*)&bias[col0 + wc + j * 16 + quad * 4];
        #pragma unroll
        for (int i = 0; i < 4; ++i) {
            const int r = row0 + wr + i * 16 + ln15;
            #pragma unroll
            for (int j = 0; j < 4; ++j) {
                const int c = col0 + wc + j * 16 + quad * 4;
                if (MODE == 1) {
                    union { short s[4]; unsigned long long u; } pk;
                    pk.s[0] = f2bf(acc[i][j][0] + b4[j].x);
                    pk.s[1] = f2bf(acc[i][j][1] + b4[j].y);
                    pk.s[2] = f2bf(acc[i][j][2] + b4[j].z);
                    pk.s[3] = f2bf(acc[i][j][3] + b4[j].w);
                    *(unsigned long long*)&((short*)Cout)[(size_t)r * N + c] = pk.u;
                } else {
                    float4 v;
                    v.x = acc[i][j][0] + b4[j].x;
                    v.y = acc[i][j][1] + b4[j].y;
                    v.z = acc[i][j][2] + b4[j].z;
                    v.w = acc[i][j][3] + b4[j].w;
                    *(float4*)&((float*)Cout)[(size_t)r * N + c] = v;
                }
            }
        }
    }
}

// ---------------------------------------------------------------------------
// QKV GEMM, 256x256 tile / BK=64 / 8 waves (2Mx4N), 4-phase-per-K-tile
// schedule with DEEP staging lead (fix of round-1 regression):
//   buffer release points: B halves last read at P2, A halves at P3 ->
//   tile kt+2's B staged at P3 of kt, A at P4 of kt. The vmcnt(8) at
//   P4-end of kt keeps only tile kt+2's 8 loads in flight and guarantees
//   tile kt+1 (issued during kt-1, 4-5 phases ago) is complete — every
//   waited-on load has ~4 phases of latency hiding (round 1 had 1 phase).
// vpath (operand order) hoisted to ONE uniform top-level branch; MFMA
// clusters kk-outer (8 independent accumulators between dependent pairs).
// ---------------------------------------------------------------------------
#define NT12 (EMB / 64)   // 12 K-tiles

#define BAR()    do { asm volatile("" ::: "memory"); __builtin_amdgcn_s_barrier(); \
                      asm volatile("" ::: "memory"); } while (0)
#define LGKM0()  asm volatile("s_waitcnt lgkmcnt(0)" ::: "memory")
#define VMC0()   asm volatile("s_waitcnt vmcnt(0)" ::: "memory")
#define VMC8()   asm volatile("s_waitcnt vmcnt(8)" ::: "memory")
#define SCHED0() __builtin_amdgcn_sched_barrier(0)
#define PRIO1()  __builtin_amdgcn_s_setprio(1)
#define PRIO0()  __builtin_amdgcn_s_setprio(0)

// swizzled fragment read: logical k-chunk q of row r lives at physical chunk q^(r&7)
#define LDA(bf_, r_, q_) (*(const short8*)&As[bf_][(r_) * 64 + ((((q_)) ^ ((r_) & 7)) << 3)])
#define LDB(bf_, r_, q_) (*(const short8*)&Bs[bf_][(r_) * 64 + ((((q_)) ^ ((r_) & 7)) << 3)])

// 16 MFMAs: acc[IB..IB+3][JB..JB+1], kk-outer for 8-wide independence.
// _T: trans path (C^T accumulate, mfma(b,a)); _D: direct (mfma(a,b)).
#define MMA_T(IB, JB)                                                        \
    _Pragma("unroll")                                                        \
    for (int kk = 0; kk < 2; ++kk)                                           \
        _Pragma("unroll")                                                    \
        for (int mi = 0; mi < 4; ++mi)                                       \
            _Pragma("unroll")                                                \
            for (int nj = 0; nj < 2; ++nj)                                   \
                acc[(IB) + mi][(JB) + nj] =                                  \
                    __builtin_amdgcn_mfma_f32_16x16x32_bf16(                 \
                        b[(JB) + nj][kk], a[mi][kk],                         \
                        acc[(IB) + mi][(JB) + nj], 0, 0, 0);

#define MMA_D(IB, JB)                                                        \
    _Pragma("unroll")                                                        \
    for (int kk = 0; kk < 2; ++kk)                                           \
        _Pragma("unroll")                                                    \
        for (int mi = 0; mi < 4; ++mi)                                       \
            _Pragma("unroll")                                                \
            for (int nj = 0; nj < 2; ++nj)                                   \
                acc[(IB) + mi][(JB) + nj] =                                  \
                    __builtin_amdgcn_mfma_f32_16x16x32_bf16(                 \
                        a[mi][kk], b[(JB) + nj][kk],                         \
                        acc[(IB) + mi][(JB) + nj], 0, 0, 0);

// One K-tile iteration loop, parameterized on the MFMA macro (uniform path).
#define KLOOP(MM)                                                            \
    for (int kt = 0; kt < NT12; ++kt) {                                      \
        const int buf = kt & 1;                                              \
        /* ---- phase 1: a lower half + b01 (12 ds_reads) ---- */            \
        _Pragma("unroll")                                                    \
        for (int mi = 0; mi < 4; ++mi)                                       \
            _Pragma("unroll")                                                \
            for (int kk = 0; kk < 2; ++kk)                                   \
                a[mi][kk] = LDA(buf, ar0 + mi * 16, quad + kk * 4);          \
        _Pragma("unroll")                                                    \
        for (int nj = 0; nj < 2; ++nj)                                       \
            _Pragma("unroll")                                                \
            for (int kk = 0; kk < 2; ++kk)                                   \
                b[nj][kk] = LDB(buf, br0 + nj * 16, quad + kk * 4);          \
        BAR(); LGKM0(); SCHED0();                                            \
        PRIO1(); MM(0, 0); PRIO0();                                          \
        BAR();                                                               \
        /* ---- phase 2: b23 (4 ds_reads) ---- */                            \
        _Pragma("unroll")                                                    \
        for (int nj = 2; nj < 4; ++nj)                                       \
            _Pragma("unroll")                                                \
            for (int kk = 0; kk < 2; ++kk)                                   \
                b[nj][kk] = LDB(buf, br0 + nj * 16, quad + kk * 4);          \
        BAR(); LGKM0(); SCHED0();                                            \
        PRIO1(); MM(0, 2); PRIO0();                                          \
        BAR();                                                               \
        /* ---- phase 3: a upper half (8 ds_reads); stage kt+2 B ---- */     \
        _Pragma("unroll")                                                    \
        for (int mi = 0; mi < 4; ++mi)                                       \
            _Pragma("unroll")                                                \
            for (int kk = 0; kk < 2; ++kk)                                   \
                a[mi][kk] = LDA(buf, ar0 + 64 + mi * 16, quad + kk * 4);     \
        stage_half(kt + 2, 2); stage_half(kt + 2, 3);                        \
        BAR(); LGKM0(); SCHED0();                                            \
        PRIO1(); MM(4, 2); PRIO0();                                          \
        BAR();                                                               \
        /* ---- phase 4: no ds_reads; stage kt+2 A ---- */                   \
        stage_half(kt + 2, 0); stage_half(kt + 2, 1);                        \
        SCHED0();                                                            \
        PRIO1(); MM(4, 0); PRIO0();                                          \
        if (kt + 2 < NT12) { VMC8(); } else { VMC0(); }                      \
        BAR();                                                               \
    }

__global__ __launch_bounds__(512, 2) void gemm_qkv_256(
    const short* __restrict__ A, const short* __restrict__ Bt,
    const float* __restrict__ bias, short* __restrict__ qkvb,
    short* __restrict__ vt)
{
    __shared__ __align__(16) short As[2][256 * 64];   // 64 KB (2 K-tile buffers)
    __shared__ __align__(16) short Bs[2][256 * 64];   // 64 KB

    const int tid  = threadIdx.x;
    const int wave = tid >> 6;
    const int lane = tid & 63;
    const int ln15 = lane & 15;
    const int quad = lane >> 4;
    const int wm   = wave >> 2;        // 0..1  (M direction, 128 rows each)
    const int wn   = wave & 3;         // 0..3  (N direction, 64 cols each)

    // XCD-bijective swizzle: 288 blocks, 36 consecutive tiles per XCD
    const int orig = blockIdx.x;
    const int wg   = (orig & 7) * 36 + (orig >> 3);
    const int bx   = wg % (QKVW / 256);   // 0..8
    const int by   = wg / (QKVW / 256);   // 0..31
    const int row0 = by * 256;
    const int col0 = bx * 256;
    const bool vpath = (col0 >= VOFF);    // tiles 6,7,8 are the V columns

    const short* Ag = A  + (size_t)row0 * EMB;
    const short* Bg = Bt + (size_t)col0 * EMB;

    // stage one half-tile of K-tile t: h = 0 (A rows 0-127), 1 (A 128-255),
    // 2 (B rows 0-127), 3 (B 128-255). 2 global_load_lds per wave per call.
    auto stage_half = [&](int t, int h) {
        if (t >= NT12) return;
        const int buf   = t & 1;
        const int k0    = t * 64;
        const int rbase = (h & 1) * 128;
        short* lb       = (h < 2) ? &As[buf][rbase * 64] : &Bs[buf][rbase * 64];
        const short* gb = (h < 2) ? Ag : Bg;
        #pragma unroll
        for (int p = 0; p < 2; ++p) {
            const int id  = p * 512 + tid;        // 0..1023
            const int row = rbase + (id >> 3);    // 0..255
            const int c   = (id & 7) ^ (row & 7); // pre-swizzled source chunk
            async_load16(gb + (size_t)row * EMB + k0 + c * 8, lb + (size_t)id * 8);
        }
    };

    floatx4 acc[8][4];
    #pragma unroll
    for (int i = 0; i < 8; ++i)
        #pragma unroll
        for (int j = 0; j < 4; ++j) acc[i][j] = (floatx4){0.f, 0.f, 0.f, 0.f};

    short8 a[4][2];   // current M-half A fragments
    short8 b[4][2];   // all four N fragments (live across phases)

    // ---- prologue: fully stage tiles 0 and 1 (8 loads each per wave) ----
    #pragma unroll
    for (int h = 0; h < 4; ++h) stage_half(0, h);
    #pragma unroll
    for (int h = 0; h < 4; ++h) stage_half(1, h);
    VMC8();           // tile 0 complete; tile 1's 8 loads stay in flight
    BAR();

    const int ar0 = wm * 128 + ln15;
    const int br0 = wn * 64 + ln15;

    if (vpath) { KLOOP(MMA_D) } else { KLOOP(MMA_T) }

    // ---- epilogue (same per-16x16 conventions as the verified 128^2 kernel) ----
    if (!vpath) {
        // trans acc: lane holds row r = ...+ln15, cols c = ...+quad*4+reg
        #pragma unroll
        for (int j = 0; j < 4; ++j) {
            const float4 b4 = *(const float4*)&bias[col0 + wn * 64 + j * 16 + quad * 4];
            #pragma unroll
            for (int i = 0; i < 8; ++i) {
                const int r = row0 + wm * 128 + i * 16 + ln15;
                const int c = col0 + wn * 64 + j * 16 + quad * 4;
                union { short s[4]; unsigned long long u; } pk;
                pk.s[0] = f2bf(acc[i][j][0] + b4.x);
                pk.s[1] = f2bf(acc[i][j][1] + b4.y);
                pk.s[2] = f2bf(acc[i][j][2] + b4.z);
                pk.s[3] = f2bf(acc[i][j][3] + b4.w);
                *(unsigned long long*)&qkvb[(size_t)r * QKVW + c] = pk.u;
            }
        }
    } else {
        // direct acc: lane holds col c = ...+ln15, rows r = ...+quad*4+reg
        #pragma unroll
        for (int j = 0; j < 4; ++j) {
            const int c  = col0 + wn * 64 + j * 16 + ln15;
            const float bv = bias[c];
            const int c2 = c - VOFF;
            #pragma unroll
            for (int i = 0; i < 8; ++i) {
                const int r = row0 + wm * 128 + i * 16 + quad * 4;
                union { short s[4]; unsigned long long u; } pk;
                #pragma unroll
                for (int reg = 0; reg < 4; ++reg)
                    pk.s[reg] = f2bf(acc[i][j][reg] + bv);
                *(unsigned long long*)&vt[(size_t)(r >> 10) * (EMB * SEQ) +
                                          (size_t)c2 * SEQ + (r & 1023)] = pk.u;
            }
        }
    }
}

// ---------------------------------------------------------------------------
// MFMA flash attention — unchanged (passing) version: 64 Q rows/block,
// vt-based V^T staging, no max-tracking, deferred l, swizzled Ps round-trip.
// ---------------------------------------------------------------------------
#define LDK 72  // padded LDS row stride (shorts): 144 B

__global__ __launch_bounds__(256) void attn_mfma(
    const short* __restrict__ qkv, const short* __restrict__ vt,
    short* __restrict__ out)
{
    __shared__ __align__(16) short Ks[64 * LDK];     // K tile [kr][d]
    __shared__ __align__(16) short Vt[64 * LDK];     // V^T tile [d][kr]
    __shared__ __align__(16) short Ps[4 * 16 * LDK]; // per-wave P, swizzled

    const int tid  = threadIdx.x;
    const int wave = tid >> 6;
    const int lane = tid & 63;
    const int ln15 = lane & 15;
    const int quad = lane >> 4;

    const int qc = 15 - (int)(blockIdx.x / (BATCH * NH));   // heavy chunks first
    const int bh = blockIdx.x % (BATCH * NH);
    const int h  = bh % NH;
    const int b  = bh / NH;

    const int q0w = qc * 64 + wave * 16;

    const short* qkv_b = qkv + (size_t)b * SEQ * QKVW + h * HD;
    const short* Kg  = qkv_b + EMB;
    const short* Vtg = vt + ((size_t)b * EMB + h * HD) * SEQ;

    short8 qf[2];
    {
        const short* qrow = qkv_b + (size_t)(q0w + ln15) * QKVW;
        qf[0] = *(const short8*)(qrow + quad * 8);
        qf[1] = *(const short8*)(qrow + quad * 8 + 32);
    }

    floatx4 o[4];
    #pragma unroll
    for (int i = 0; i < 4; ++i) o[i] = (floatx4){0.f, 0.f, 0.f, 0.f};
    float lp[4] = {0.f, 0.f, 0.f, 0.f};   // per-lane l partials

    const int rr = tid >> 3;          // 0..31
    const int c8 = (tid & 7) * 8;     // 0..56

    for (int kt = 0; kt <= qc; ++kt) {
        // ---- stage K rows and V^T rows, b128 writes (conflict-free) ----
        #pragma unroll
        for (int p = 0; p < 2; ++p) {
            const int r2 = rr + p * 32;
            *(uint4*)&Ks[r2 * LDK + c8] =
                *(const uint4*)(Kg + (size_t)(kt * 64 + r2) * QKVW + c8);
            *(uint4*)&Vt[r2 * LDK + c8] =
                *(const uint4*)(Vtg + (size_t)r2 * SEQ + kt * 64 + c8);
        }
        __syncthreads();

        // ---- S = Q · K^T ----
        floatx4 s[4];
        #pragma unroll
        for (int i = 0; i < 4; ++i) s[i] = (floatx4){0.f, 0.f, 0.f, 0.f};
        #pragma unroll
        for (int st = 0; st < 2; ++st)
            #pragma unroll
            for (int sub = 0; sub < 4; ++sub) {
                const short8 kf = *(const short8*)&Ks[(ln15 + sub * 16) * LDK + quad * 8 + st * 32];
                s[sub] = __builtin_amdgcn_mfma_f32_16x16x32_bf16(qf[st], kf, s[sub], 0, 0, 0);
            }

        // ---- P = exp(S/8), causal mask on diagonal tile, accumulate l ----
        const bool diag = (kt == qc);
        #pragma unroll
        for (int sub = 0; sub < 4; ++sub)
            #pragma unroll
            for (int reg = 0; reg < 4; ++reg) {
                float pv = __expf(s[sub][reg] * 0.125f);
                if (diag && (ln15 + sub * 16 > wave * 16 + quad * 4 + reg)) pv = 0.f;
                s[sub][reg] = pv;
            }
        #pragma unroll
        for (int reg = 0; reg < 4; ++reg)
            lp[reg] += (s[0][reg] + s[1][reg]) + (s[2][reg] + s[3][reg]);

        // ---- P (C-layout) -> swizzled LDS -> A-layout fragments ----
        short* Pw = &Ps[wave * 16 * LDK];
        #pragma unroll
        for (int sub = 0; sub < 4; ++sub)
            #pragma unroll
            for (int reg = 0; reg < 4; ++reg) {
                const int qr   = quad * 4 + reg;
                const int kr8  = sub * 2 + (ln15 >> 3);
                const int slot = (kr8 + 5 * quad + reg) & 7;
                Pw[qr * LDK + slot * 8 + (ln15 & 7)] = f2bf(s[sub][reg]);
            }

        short8 pf[2];
        #pragma unroll
        for (int st = 0; st < 2; ++st) {
            const int slot = ((quad + 4 * st) + 5 * (ln15 >> 2) + (ln15 & 3)) & 7;
            pf[st] = *(const short8*)&Pw[ln15 * LDK + slot * 8];
        }

        // ---- O += P · V ----
        #pragma unroll
        for (int st = 0; st < 2; ++st)
            #pragma unroll
            for (int sub = 0; sub < 4; ++sub) {
                const short8 vf = *(const short8*)&Vt[(ln15 + sub * 16) * LDK + quad * 8 + st * 32];
                o[sub] = __builtin_amdgcn_mfma_f32_16x16x32_bf16(pf[st], vf, o[sub], 0, 0, 0);
            }

        __syncthreads();
    }

    // ---- epilogue: reduce l across the 16 lanes of each row, write O/l ----
    #pragma unroll
    for (int reg = 0; reg < 4; ++reg) {
        float t = lp[reg];
        #pragma unroll
        for (int off = 1; off <= 8; off <<= 1)
            t += __shfl_xor(t, off, 64);
        const float inv = 1.0f / t;
        const size_t row = (size_t)(b * SEQ + q0w + quad * 4 + reg) * EMB + h * HD;
        #pragma unroll
        for (int sub = 0; sub < 4; ++sub)
            out[row + ln15 + sub * 16] = f2bf(o[sub][reg] * inv);
    }
}

// ---------------------------------------------------------------------------
extern "C" void kernel_launch(void* const* d_in, const int* in_sizes, int n_in,
                              void* d_out, int out_size, void* d_ws, size_t ws_size,
                              hipStream_t stream)
{
    const float* x      = (const float*)d_in[0];   // [8,1024,768]
    const float* w_attn = (const float*)d_in[1];   // [768, 2304]
    const float* b_attn = (const float*)d_in[2];   // [2304]
    const float* w_proj = (const float*)d_in[3];   // [768, 768]
    const float* b_proj = (const float*)d_in[4];   // [768]
    float* out = (float*)d_out;                    // [8,1024,768] fp32

    const int M = BATCH * SEQ;       // 8192

    short* xb    = (short*)d_ws;                          // [8192, 768]
    short* waT   = xb    + (size_t)M * EMB;               // [2304, 768]
    short* wpT   = waT   + (size_t)QKVW * EMB;            // [768, 768]
    short* qkvb  = wpT   + (size_t)EMB * EMB;             // [8192, 2304] (V third unused)
    short* vtb   = qkvb  + (size_t)M * QKVW;              // [8, 768, 1024] V^T per head
    short* attnb = vtb   + (size_t)BATCH * EMB * SEQ;     // [8192, 768]

    dim3 blk(256);

    // 0) conversions
    cvt_bf16<<<dim3((M * EMB) / 8 / 256), blk, 0, stream>>>(x, xb, (M * EMB) / 8);
    transpose_to_bf16<<<dim3(QKVW / 32, EMB / 32), blk, 0, stream>>>(w_attn, waT, EMB, QKVW);
    transpose_to_bf16<<<dim3(EMB / 32, EMB / 32), blk, 0, stream>>>(w_proj, wpT, EMB, EMB);

    // 1) qkv = x @ w_attn + b_attn  — 256^2 deep-lead schedule
    //    (Q/K -> qkvb bf16, V -> vtb transposed). 288 blocks x 512 threads.
    gemm_qkv_256<<<dim3((QKVW / 256) * (M / 256)), dim3(512), 0, stream>>>(
        xb, waT, b_attn, qkvb, vtb);

    // 2) causal MFMA flash attention -> attnb (bf16)
    attn_mfma<<<dim3(16 * BATCH * NH), blk, 0, stream>>>(qkvb, vtb, attnb);

    // 3) out = attn @ w_proj + b_proj  (fp32 out)
    gemm_bf16<0><<<dim3(EMB / 128, M / 128), blk, 0, stream>>>(
        attnb, wpT, b_proj, out, nullptr, M, EMB, EMB);
}

// Round 3
// 206.598 us; speedup vs baseline: 1.1470x; 1.0459x over previous
//
#include <hip/hip_runtime.h>
#include <hip/hip_bf16.h>
#include <math.h>

// Problem constants (B=8, T=1024, EMB=768, H=12, D=64)
#define BATCH 8
#define SEQ   1024
#define EMB   768
#define NH    12
#define HD    64
#define QKVW  (3 * EMB)   // 2304
#define VOFF  (2 * EMB)   // 1536 — start of V columns in qkv

typedef short short8   __attribute__((ext_vector_type(8)));
typedef float floatx4  __attribute__((ext_vector_type(4)));

// fp32 -> bf16 (RNE) as raw short
__device__ __forceinline__ short f2bf(float f) {
    union { float f; unsigned u; } v; v.f = f;
    unsigned r = (v.u + 0x7fffu + ((v.u >> 16) & 1u)) >> 16;
    return (short)r;
}

// async 16B global -> LDS (wave-uniform base + lane*16 on the LDS side)
__device__ __forceinline__ void async_load16(const void* g, void* l) {
    __builtin_amdgcn_global_load_lds(
        (const __attribute__((address_space(1))) unsigned int*)g,
        (__attribute__((address_space(3))) unsigned int*)l, 16, 0, 0);
}

// ---------------------------------------------------------------------------
// fp32 -> bf16 elementwise (8 elems/thread)
// ---------------------------------------------------------------------------
__global__ __launch_bounds__(256) void cvt_bf16(
    const float* __restrict__ in, short* __restrict__ out, int n8)
{
    const int i = blockIdx.x * 256 + threadIdx.x;
    if (i >= n8) return;
    const float4 a = ((const float4*)in)[2 * i];
    const float4 b = ((const float4*)in)[2 * i + 1];
    short8 s;
    s[0] = f2bf(a.x); s[1] = f2bf(a.y); s[2] = f2bf(a.z); s[3] = f2bf(a.w);
    s[4] = f2bf(b.x); s[5] = f2bf(b.y); s[6] = f2bf(b.z); s[7] = f2bf(b.w);
    ((short8*)out)[i] = s;
}

// ---------------------------------------------------------------------------
// fp32 [R,C] -> bf16 [C,R] (transpose). R,C multiples of 32. Block 256 = 32x8.
// ---------------------------------------------------------------------------
__global__ __launch_bounds__(256) void transpose_to_bf16(
    const float* __restrict__ in, short* __restrict__ outT, int R, int C)
{
    __shared__ float t[32][33];
    const int c0 = blockIdx.x * 32, r0 = blockIdx.y * 32;
    const int lx = threadIdx.x & 31, ly = threadIdx.x >> 5;
    #pragma unroll
    for (int i = 0; i < 32; i += 8)
        t[ly + i][lx] = in[(size_t)(r0 + ly + i) * C + c0 + lx];
    __syncthreads();
    #pragma unroll
    for (int i = 0; i < 32; i += 8)
        outT[(size_t)(c0 + ly + i) * R + r0 + lx] = f2bf(t[lx][ly + i]);
}

// ---------------------------------------------------------------------------
// Pipelined bf16 MFMA GEMM: 128x192 tile / BK=64 / 6 waves (2M x 3N),
// per-wave 64x64 (legacy acc[4][4] fragment+epilogue conventions).
// LDS = 80 KiB -> 2 blocks/CU (12 waves/CU). Deep-lead 2-phase schedule:
//   P1: read all A frags + b01, stage B(kt+1)  [A region retires at P1-end]
//   P2: read b23, stage A(kt+2)                [B region retires at P2-end]
//   one counted vmcnt per K-tile at P2-end: waves 0-3 keep their 4 A(kt+2)
//   loads in flight (vmcnt(4)), waves 4-5 drain (vmcnt(0)).
// Leads: A = 3 phases, B = 2 phases (B is the L2-hot weight panel).
// MODE 0: proj (fp32 out + b_proj). MODE 1: qkv (bf16 out; V cols -> vt).
// K = EMB for both uses; N passed (2304 or 768), N % 192 == 0.
// ---------------------------------------------------------------------------
#define NT12 (EMB / 64)   // 12 K-tiles

#define BAR()    do { asm volatile("" ::: "memory"); __builtin_amdgcn_s_barrier(); \
                      asm volatile("" ::: "memory"); } while (0)
#define LGKM0()  asm volatile("s_waitcnt lgkmcnt(0)" ::: "memory")
#define VMC0()   asm volatile("s_waitcnt vmcnt(0)" ::: "memory")
#define VMC4()   asm volatile("s_waitcnt vmcnt(4)" ::: "memory")
#define SCHED0() __builtin_amdgcn_sched_barrier(0)
#define PRIO1()  __builtin_amdgcn_s_setprio(1)
#define PRIO0()  __builtin_amdgcn_s_setprio(0)

// swizzled fragment read: logical k-chunk q of row r lives at physical chunk q^(r&7)
#define LDA8(bf_, r_, q_) (*(const short8*)&As[bf_][(r_) * 64 + ((((q_)) ^ ((r_) & 7)) << 3)])
#define LDB8(bf_, r_, q_) (*(const short8*)&Bs[bf_][(r_) * 64 + ((((q_)) ^ ((r_) & 7)) << 3)])

// 16 MFMAs: acc[0..3][JB..JB+1], kk-outer (8 independent between dep pairs).
// _T: trans path (C^T accumulate, mfma(b,a)); _D: direct (mfma(a,b)).
#define MMA_T2(JB)                                                           \
    _Pragma("unroll")                                                        \
    for (int kk = 0; kk < 2; ++kk)                                           \
        _Pragma("unroll")                                                    \
        for (int mi = 0; mi < 4; ++mi)                                       \
            _Pragma("unroll")                                                \
            for (int nj = 0; nj < 2; ++nj)                                   \
                acc[mi][(JB) + nj] =                                         \
                    __builtin_amdgcn_mfma_f32_16x16x32_bf16(                 \
                        b[(JB) + nj][kk], a[mi][kk],                         \
                        acc[mi][(JB) + nj], 0, 0, 0);

#define MMA_D2(JB)                                                           \
    _Pragma("unroll")                                                        \
    for (int kk = 0; kk < 2; ++kk)                                           \
        _Pragma("unroll")                                                    \
        for (int mi = 0; mi < 4; ++mi)                                       \
            _Pragma("unroll")                                                \
            for (int nj = 0; nj < 2; ++nj)                                   \
                acc[mi][(JB) + nj] =                                         \
                    __builtin_amdgcn_mfma_f32_16x16x32_bf16(                 \
                        a[mi][kk], b[(JB) + nj][kk],                         \
                        acc[mi][(JB) + nj], 0, 0, 0);

#define KLOOP2(MM)                                                           \
    for (int kt = 0; kt < NT12; ++kt) {                                      \
        const int buf = kt & 1;                                              \
        /* ---- P1: all A frags (8) + b01 (4); stage B(kt+1) ---- */         \
        _Pragma("unroll")                                                    \
        for (int mi = 0; mi < 4; ++mi)                                       \
            _Pragma("unroll")                                                \
            for (int kk = 0; kk < 2; ++kk)                                   \
                a[mi][kk] = LDA8(buf, ar0 + mi * 16, quad + kk * 4);         \
        _Pragma("unroll")                                                    \
        for (int nj = 0; nj < 2; ++nj)                                       \
            _Pragma("unroll")                                                \
            for (int kk = 0; kk < 2; ++kk)                                   \
                b[nj][kk] = LDB8(buf, br0 + nj * 16, quad + kk * 4);         \
        if (kt + 1 < NT12) stage_B(kt + 1);                                  \
        BAR(); LGKM0(); SCHED0();                                            \
        PRIO1(); MM(0); PRIO0();                                             \
        BAR();                                                               \
        /* ---- P2: b23 (4); stage A(kt+2); counted wait ---- */             \
        _Pragma("unroll")                                                    \
        for (int nj = 2; nj < 4; ++nj)                                       \
            _Pragma("unroll")                                                \
            for (int kk = 0; kk < 2; ++kk)                                   \
                b[nj][kk] = LDB8(buf, br0 + nj * 16, quad + kk * 4);         \
        if (kt + 2 < NT12) stage_A(kt + 2);                                  \
        BAR(); LGKM0(); SCHED0();                                            \
        PRIO1(); MM(2); PRIO0();                                             \
        if (kt + 2 < NT12) {                                                 \
            if (wuni < 4) { VMC4(); } else { VMC0(); }                       \
        } else if (kt + 1 < NT12) { VMC0(); }                                \
        BAR();                                                               \
    }

template <int MODE>
__global__ __launch_bounds__(384, 3) void gemm_pipe(
    const short* __restrict__ A, const short* __restrict__ Bt,
    const float* __restrict__ bias, void* __restrict__ Cout,
    short* __restrict__ vt, int N, int nbx)
{
    __shared__ __align__(16) short As[2][128 * 64];   // 2 x 16 KB
    __shared__ __align__(16) short Bs[2][192 * 64];   // 2 x 24 KB  (total 80 KB)

    const int tid  = threadIdx.x;
    const int wave = tid >> 6;
    const int lane = tid & 63;
    const int ln15 = lane & 15;
    const int quad = lane >> 4;
    const int wm   = wave / 3;         // 0..1  (M, 64 rows each)
    const int wn   = wave % 3;         // 0..2  (N, 64 cols each)
    const int wuni = __builtin_amdgcn_readfirstlane(wave);  // uniform wave id

    // XCD-bijective swizzle: nwg = 64*nbx (divisible by 8); 8*nbx blocks/XCD
    const int orig = blockIdx.x;
    const int wg   = (orig & 7) * (8 * nbx) + (orig >> 3);
    const int bx   = wg % nbx;
    const int by   = wg / nbx;
    const int row0 = by * 128;
    const int col0 = bx * 192;
    const bool vpath = (MODE == 1) && (col0 >= VOFF);  // QKV V cols (bx>=8)

    const short* Ag = A  + (size_t)row0 * EMB;
    const short* Bg = Bt + (size_t)col0 * EMB;

    // ---- staging: 1-KB chunks, pre-swizzled global source (rule 21) ----
    // A: 16 chunks (128 rows), waves 0-3 x 4.  B: 24 chunks (192 rows), all x 4.
    auto stage_A = [&](int t) {
        if (wave >= 4) return;
        const int buf = t & 1;
        #pragma unroll
        for (int p = 0; p < 4; ++p) {
            const int id  = (wave * 4 + p) * 64 + lane;  // 0..1023
            const int row = id >> 3;                     // 0..127
            const int c   = (id & 7) ^ (row & 7);
            async_load16(Ag + (size_t)row * EMB + t * 64 + c * 8, &As[buf][id * 8]);
        }
    };
    auto stage_B = [&](int t) {
        const int buf = t & 1;
        #pragma unroll
        for (int p = 0; p < 4; ++p) {
            const int id  = (wave * 4 + p) * 64 + lane;  // 0..1535
            const int row = id >> 3;                     // 0..191
            const int c   = (id & 7) ^ (row & 7);
            async_load16(Bg + (size_t)row * EMB + t * 64 + c * 8, &Bs[buf][id * 8]);
        }
    };

    floatx4 acc[4][4];
    #pragma unroll
    for (int i = 0; i < 4; ++i)
        #pragma unroll
        for (int j = 0; j < 4; ++j) acc[i][j] = (floatx4){0.f, 0.f, 0.f, 0.f};

    short8 a[4][2];
    short8 b[4][2];

    // ---- prologue: A(0), B(0), A(1); keep A(1) in flight ----
    stage_A(0); stage_B(0); stage_A(1);
    if (wuni < 4) { VMC4(); } else { VMC0(); }
    BAR();

    const int ar0 = wm * 64 + ln15;
    const int br0 = wn * 64 + ln15;

    if (vpath) { KLOOP2(MMA_D2) } else { KLOOP2(MMA_T2) }

    // ---- epilogue (legacy per-16x16 conventions, per-wave 64x64) ----
    const int wr = wm * 64, wc = wn * 64;
    if (vpath) {
        // direct acc: lane holds col c = ...+ln15, rows r = ...+quad*4+reg
        #pragma unroll
        for (int j = 0; j < 4; ++j) {
            const int c  = col0 + wc + j * 16 + ln15;
            const float bv = bias[c];
            const int c2 = c - VOFF;
            #pragma unroll
            for (int i = 0; i < 4; ++i) {
                const int r = row0 + wr + i * 16 + quad * 4;
                union { short s[4]; unsigned long long u; } pk;
                #pragma unroll
                for (int reg = 0; reg < 4; ++reg)
                    pk.s[reg] = f2bf(acc[i][j][reg] + bv);
                *(unsigned long long*)&vt[(size_t)(r >> 10) * (EMB * SEQ) +
                                          (size_t)c2 * SEQ + (r & 1023)] = pk.u;
            }
        }
    } else {
        // trans acc: lane holds row r = ...+ln15, cols c = ...+quad*4+reg
        float4 b4[4];
        #pragma unroll
        for (int j = 0; j < 4; ++j)
            b4[j] = *(const float4*)&bias[col0 + wc + j * 16 + quad * 4];
        #pragma unroll
        for (int i = 0; i < 4; ++i) {
            const int r = row0 + wr + i * 16 + ln15;
            #pragma unroll
            for (int j = 0; j < 4; ++j) {
                const int c = col0 + wc + j * 16 + quad * 4;
                if (MODE == 1) {
                    union { short s[4]; unsigned long long u; } pk;
                    pk.s[0] = f2bf(acc[i][j][0] + b4[j].x);
                    pk.s[1] = f2bf(acc[i][j][1] + b4[j].y);
                    pk.s[2] = f2bf(acc[i][j][2] + b4[j].z);
                    pk.s[3] = f2bf(acc[i][j][3] + b4[j].w);
                    *(unsigned long long*)&((short*)Cout)[(size_t)r * N + c] = pk.u;
                } else {
                    float4 v;
                    v.x = acc[i][j][0] + b4[j].x;
                    v.y = acc[i][j][1] + b4[j].y;
                    v.z = acc[i][j][2] + b4[j].z;
                    v.w = acc[i][j][3] + b4[j].w;
                    *(float4*)&((float*)Cout)[(size_t)r * N + c] = v;
                }
            }
        }
    }
}

// ---------------------------------------------------------------------------
// MFMA flash attention — unchanged (passing) version: 64 Q rows/block,
// vt-based V^T staging, no max-tracking, deferred l, swizzled Ps round-trip.
// ---------------------------------------------------------------------------
#define LDK 72  // padded LDS row stride (shorts): 144 B

__global__ __launch_bounds__(256) void attn_mfma(
    const short* __restrict__ qkv, const short* __restrict__ vt,
    short* __restrict__ out)
{
    __shared__ __align__(16) short Ks[64 * LDK];     // K tile [kr][d]
    __shared__ __align__(16) short Vt[64 * LDK];     // V^T tile [d][kr]
    __shared__ __align__(16) short Ps[4 * 16 * LDK]; // per-wave P, swizzled

    const int tid  = threadIdx.x;
    const int wave = tid >> 6;
    const int lane = tid & 63;
    const int ln15 = lane & 15;
    const int quad = lane >> 4;

    const int qc = 15 - (int)(blockIdx.x / (BATCH * NH));   // heavy chunks first
    const int bh = blockIdx.x % (BATCH * NH);
    const int h  = bh % NH;
    const int b  = bh / NH;

    const int q0w = qc * 64 + wave * 16;

    const short* qkv_b = qkv + (size_t)b * SEQ * QKVW + h * HD;
    const short* Kg  = qkv_b + EMB;
    const short* Vtg = vt + ((size_t)b * EMB + h * HD) * SEQ;

    short8 qf[2];
    {
        const short* qrow = qkv_b + (size_t)(q0w + ln15) * QKVW;
        qf[0] = *(const short8*)(qrow + quad * 8);
        qf[1] = *(const short8*)(qrow + quad * 8 + 32);
    }

    floatx4 o[4];
    #pragma unroll
    for (int i = 0; i < 4; ++i) o[i] = (floatx4){0.f, 0.f, 0.f, 0.f};
    float lp[4] = {0.f, 0.f, 0.f, 0.f};   // per-lane l partials

    const int rr = tid >> 3;          // 0..31
    const int c8 = (tid & 7) * 8;     // 0..56

    for (int kt = 0; kt <= qc; ++kt) {
        // ---- stage K rows and V^T rows, b128 writes (conflict-free) ----
        #pragma unroll
        for (int p = 0; p < 2; ++p) {
            const int r2 = rr + p * 32;
            *(uint4*)&Ks[r2 * LDK + c8] =
                *(const uint4*)(Kg + (size_t)(kt * 64 + r2) * QKVW + c8);
            *(uint4*)&Vt[r2 * LDK + c8] =
                *(const uint4*)(Vtg + (size_t)r2 * SEQ + kt * 64 + c8);
        }
        __syncthreads();

        // ---- S = Q · K^T ----
        floatx4 s[4];
        #pragma unroll
        for (int i = 0; i < 4; ++i) s[i] = (floatx4){0.f, 0.f, 0.f, 0.f};
        #pragma unroll
        for (int st = 0; st < 2; ++st)
            #pragma unroll
            for (int sub = 0; sub < 4; ++sub) {
                const short8 kf = *(const short8*)&Ks[(ln15 + sub * 16) * LDK + quad * 8 + st * 32];
                s[sub] = __builtin_amdgcn_mfma_f32_16x16x32_bf16(qf[st], kf, s[sub], 0, 0, 0);
            }

        // ---- P = exp(S/8), causal mask on diagonal tile, accumulate l ----
        const bool diag = (kt == qc);
        #pragma unroll
        for (int sub = 0; sub < 4; ++sub)
            #pragma unroll
            for (int reg = 0; reg < 4; ++reg) {
                float pv = __expf(s[sub][reg] * 0.125f);
                if (diag && (ln15 + sub * 16 > wave * 16 + quad * 4 + reg)) pv = 0.f;
                s[sub][reg] = pv;
            }
        #pragma unroll
        for (int reg = 0; reg < 4; ++reg)
            lp[reg] += (s[0][reg] + s[1][reg]) + (s[2][reg] + s[3][reg]);

        // ---- P (C-layout) -> swizzled LDS -> A-layout fragments ----
        short* Pw = &Ps[wave * 16 * LDK];
        #pragma unroll
        for (int sub = 0; sub < 4; ++sub)
            #pragma unroll
            for (int reg = 0; reg < 4; ++reg) {
                const int qr   = quad * 4 + reg;
                const int kr8  = sub * 2 + (ln15 >> 3);
                const int slot = (kr8 + 5 * quad + reg) & 7;
                Pw[qr * LDK + slot * 8 + (ln15 & 7)] = f2bf(s[sub][reg]);
            }

        short8 pf[2];
        #pragma unroll
        for (int st = 0; st < 2; ++st) {
            const int slot = ((quad + 4 * st) + 5 * (ln15 >> 2) + (ln15 & 3)) & 7;
            pf[st] = *(const short8*)&Pw[ln15 * LDK + slot * 8];
        }

        // ---- O += P · V ----
        #pragma unroll
        for (int st = 0; st < 2; ++st)
            #pragma unroll
            for (int sub = 0; sub < 4; ++sub) {
                const short8 vf = *(const short8*)&Vt[(ln15 + sub * 16) * LDK + quad * 8 + st * 32];
                o[sub] = __builtin_amdgcn_mfma_f32_16x16x32_bf16(pf[st], vf, o[sub], 0, 0, 0);
            }

        __syncthreads();
    }

    // ---- epilogue: reduce l across the 16 lanes of each row, write O/l ----
    #pragma unroll
    for (int reg = 0; reg < 4; ++reg) {
        float t = lp[reg];
        #pragma unroll
        for (int off = 1; off <= 8; off <<= 1)
            t += __shfl_xor(t, off, 64);
        const float inv = 1.0f / t;
        const size_t row = (size_t)(b * SEQ + q0w + quad * 4 + reg) * EMB + h * HD;
        #pragma unroll
        for (int sub = 0; sub < 4; ++sub)
            out[row + ln15 + sub * 16] = f2bf(o[sub][reg] * inv);
    }
}

// ---------------------------------------------------------------------------
extern "C" void kernel_launch(void* const* d_in, const int* in_sizes, int n_in,
                              void* d_out, int out_size, void* d_ws, size_t ws_size,
                              hipStream_t stream)
{
    const float* x      = (const float*)d_in[0];   // [8,1024,768]
    const float* w_attn = (const float*)d_in[1];   // [768, 2304]
    const float* b_attn = (const float*)d_in[2];   // [2304]
    const float* w_proj = (const float*)d_in[3];   // [768, 768]
    const float* b_proj = (const float*)d_in[4];   // [768]
    float* out = (float*)d_out;                    // [8,1024,768] fp32

    const int M = BATCH * SEQ;       // 8192

    short* xb    = (short*)d_ws;                          // [8192, 768]
    short* waT   = xb    + (size_t)M * EMB;               // [2304, 768]
    short* wpT   = waT   + (size_t)QKVW * EMB;            // [768, 768]
    short* qkvb  = wpT   + (size_t)EMB * EMB;             // [8192, 2304] (V third unused)
    short* vtb   = qkvb  + (size_t)M * QKVW;              // [8, 768, 1024] V^T per head
    short* attnb = vtb   + (size_t)BATCH * EMB * SEQ;     // [8192, 768]

    dim3 blk(256);

    // 0) conversions
    cvt_bf16<<<dim3((M * EMB) / 8 / 256), blk, 0, stream>>>(x, xb, (M * EMB) / 8);
    transpose_to_bf16<<<dim3(QKVW / 32, EMB / 32), blk, 0, stream>>>(w_attn, waT, EMB, QKVW);
    transpose_to_bf16<<<dim3(EMB / 32, EMB / 32), blk, 0, stream>>>(w_proj, wpT, EMB, EMB);

    // 1) qkv = x @ w_attn + b_attn — 128x192 pipelined kernel, 768 blocks,
    //    2 blocks/CU (Q/K -> qkvb bf16, V -> vtb transposed).
    gemm_pipe<1><<<dim3((M / 128) * (QKVW / 192)), dim3(384), 0, stream>>>(
        xb, waT, b_attn, qkvb, vtb, QKVW, QKVW / 192);

    // 2) causal MFMA flash attention -> attnb (bf16)
    attn_mfma<<<dim3(16 * BATCH * NH), blk, 0, stream>>>(qkvb, vtb, attnb);

    // 3) out = attn @ w_proj + b_proj — same kernel, grid exactly 256
    gemm_pipe<0><<<dim3((M / 128) * (EMB / 192)), dim3(384), 0, stream>>>(
        attnb, wpT, b_proj, out, nullptr, EMB, EMB / 192);
}